// Round 2
// baseline (512.963 us; speedup 1.0000x reference)
//
#include <hip/hip_runtime.h>
#include <cstdint>
#include <cstddef>

// ---------------------------------------------------------------------------
// MultiHeadCrossAttention W8A8 fake-quant, MI355X (gfx950)
// B=2, N=4096, M=512, C=2048, H=16, Dh=128
//
// R5: attn64 rebuilt with the counted-vmcnt pipeline (T3/T4/T5):
//   - K and V processed in 8 subgroups of 64 keys, double-buffered in the
//     existing 32KB sKV (2 x 16KB).  Subgroup sg+1's 4 gld16 are issued
//     during subgroup sg's MFMA; steady-state wait is vmcnt(4), never a
//     cold drain.
//   - V[0] prefetched BEFORE softmax; softmax barriers are lgkmcnt(0)-only
//     (raw s_barrier), so V loads stay in flight under the expf phase.
//   - P double-buffered in sQP (2 x 8 chunks; Q region dead after S-phase);
//     P[sg+1] written during subgroup sg's compute.
//   - setprio(1/0) around each 16-MFMA cluster.
// gemm_pk8 (R4 deep pipeline) unchanged.
//
// GEMM-operand pack (M x K, 128-row panels, 32-col chunk groups):
//   idx(row,col) = ((p*KT + kt)*8 + c)*512 + (quad*16 + lm)*8 + j
//   p=row>>7, c=(row>>4)&7, lm=row&15, kt=col>>5, quad=(col>>3)&3, j=col&7
// ---------------------------------------------------------------------------

typedef __bf16 bf16_t;
typedef __bf16 bf16x8 __attribute__((ext_vector_type(8)));
typedef float f32x4 __attribute__((ext_vector_type(4)));

__device__ __forceinline__ void gld16(void* lds, const void* g) {
    __builtin_amdgcn_global_load_lds(
        (__attribute__((address_space(1))) uint32_t*)(uintptr_t)g,
        (__attribute__((address_space(3))) uint32_t*)(uint32_t)(uintptr_t)lds,
        16, 0, 0);
}

__device__ __forceinline__ void load8(const float* p, int i, float* v) {
    const float4* p4 = (const float4*)p;
    float4 a = p4[2 * i], b = p4[2 * i + 1];
    v[0] = a.x; v[1] = a.y; v[2] = a.z; v[3] = a.w;
    v[4] = b.x; v[5] = b.y; v[6] = b.z; v[7] = b.w;
}
__device__ __forceinline__ void load8(const bf16_t* p, int i, float* v) {
    bf16x8 t = ((const bf16x8*)p)[i];
#pragma unroll
    for (int j = 0; j < 8; ++j) v[j] = (float)t[j];
}

// ---------------------------------------------------------------------------
// Per-row fake-quant (QUANT=1) or plain convert (QUANT=0), output packed.
// ---------------------------------------------------------------------------
template <int QUANT, typename T>
__global__ __launch_bounds__(256) void rowpack(const T* __restrict__ in,
                                               bf16_t* __restrict__ out, int K) {
    const int tid = threadIdx.x;
    const size_t row = blockIdx.x;
    const T* rp = in + row * (size_t)K;
    const int n8 = K >> 3;
    float scale = 1.0f;
    if (QUANT) {
        float m = 0.f;
        for (int i = tid; i < n8; i += 256) {
            float v[8];
            load8(rp, i, v);
#pragma unroll
            for (int j = 0; j < 8; ++j) m = fmaxf(m, fabsf(v[j]));
        }
        __shared__ float red[256];
        red[tid] = m;
        __syncthreads();
        for (int s = 128; s > 0; s >>= 1) {
            if (tid < s) red[tid] = fmaxf(red[tid], red[tid + s]);
            __syncthreads();
        }
        scale = fmaxf(red[0] * (1.0f / 127.0f), 1e-8f);
    }
    const int KT = K >> 5;
    const int p = (int)(row >> 7), c = ((int)row >> 4) & 7, lm = (int)row & 15;
    for (int i = tid; i < n8; i += 256) {
        const int col = i << 3;
        const int kt = col >> 5, quad = (col >> 3) & 3;
        float v[8];
        load8(rp, i, v);
        bf16x8 o8;
#pragma unroll
        for (int j = 0; j < 8; ++j) {
            float q = v[j];
            if (QUANT) {
                q = rintf(q / scale);  // RNE, matches jnp.round
                q = fminf(127.f, fmaxf(-127.f, q)) * scale;
            }
            o8[j] = (bf16_t)q;
        }
        const size_t dst = ((size_t)(p * KT + kt) * 8 + c) * 512 + (quad * 16 + lm) * 8;
        *(bf16x8*)(out + dst) = o8;
    }
}

// ---------------------------------------------------------------------------
// Epilogue stores (shared by the GEMM kernels).
// MODE 0: attention-packed q.  MODE 1: natural fp32.  MODE 2: kv split pack.
// ---------------------------------------------------------------------------
template <int MODE>
__device__ __forceinline__ void epi_store(void* C, int N, int row, int col, float v) {
    if (MODE == 1) {
        ((float*)C)[(size_t)row * N + col] = v;
    } else if (MODE == 0) {
        const int b = row >> 12, n = row & 4095;
        const int h = col >> 7, d = col & 127;
        const int p = n >> 6, mt = (n >> 4) & 3, lmq = n & 15;
        const int kq = d >> 5, qq = (d >> 3) & 3, jq = d & 7;
        const size_t idx = (((size_t)(b * 16 + h) * 64 + p) * 16 + kq * 4 + mt) * 512 +
                           (qq * 16 + lmq) * 8 + jq;
        ((bf16_t*)C)[idx] = (bf16_t)v;
    } else {
        const int b = row >> 9, m = row & 511;
        const int half = col >> 11, h = (col >> 7) & 15, d = col & 127;
        const int t8 = m >> 6;
        bf16_t* out = (bf16_t*)C;
        if (half == 0) {
            const int nt = (m >> 4) & 3, lmk = m & 15;
            const int kc = d >> 5, qk = (d >> 3) & 3, jk = d & 7;
            const size_t idx = (((size_t)(b * 16 + h) * 8 + t8) * 16 + kc * 4 + nt) * 512 +
                               (qk * 16 + lmk) * 8 + jk;
            out[idx] = (bf16_t)v;
        } else {
            const int kv2 = (m >> 5) & 1, qv = (m >> 3) & 3, jv = m & 7;
            const int ntv = d >> 4, lmv = d & 15;
            const size_t idx = 2097152 +
                (((size_t)(b * 16 + h) * 8 + t8) * 16 + kv2 * 8 + ntv) * 512 +
                (qv * 16 + lmv) * 8 + jv;
            out[idx] = (bf16_t)v;
        }
    }
}

// ---------------------------------------------------------------------------
// Stage one 256x64 K-tile pair (A and B) into LDS: 32 chunks each, 8 waves
// x 4 chunks, 8 gld16/thread.
// ---------------------------------------------------------------------------
__device__ __forceinline__ void stage_tile256(const bf16_t* __restrict__ A,
                                              const bf16_t* __restrict__ B,
                                              bf16_t* sa, bf16_t* sb,
                                              int pa, int pb, int KT, int t,
                                              int w, int l) {
#pragma unroll
    for (int it = 0; it < 4; ++it) {
        const int ci = w * 4 + it;                      // 0..31, wave-uniform
        const int h = ci >> 4, kt2 = (ci >> 3) & 1, c = ci & 7;
        const size_t ga = (((size_t)(pa + h) * KT + (2 * t + kt2)) * 8 + c) * 512 + l * 8;
        const size_t gb = (((size_t)(pb + h) * KT + (2 * t + kt2)) * 8 + c) * 512 + l * 8;
        gld16(sa + ci * 512, A + ga);
        gld16(sb + ci * 512, B + gb);
    }
}

// ---------------------------------------------------------------------------
// 256x256 deep-pipelined GEMM on packed operands: C = A B^T + bias.
// (unchanged from R4 — see header comment)
// ---------------------------------------------------------------------------
template <int MODE>
__global__ __launch_bounds__(512, 1) void gemm_pk8(const bf16_t* __restrict__ A,
                                                   const bf16_t* __restrict__ B,
                                                   const float* __restrict__ bias,
                                                   void* __restrict__ C,
                                                   int N, int K) {
    __shared__ __align__(16) bf16_t sA[2][16384];  // 2 x 32KB
    __shared__ __align__(16) bf16_t sB[2][16384];  // total 128KB -> 1 block/CU

    const int tid = threadIdx.x;
    const int l = tid & 63, w = tid >> 6;
    const int lm = l & 15, quad = l >> 4;
    const int wm = w & 1, wn = w >> 1;  // 2 x 4 wave grid

    const int nwg = gridDim.x;
    const int bid = blockIdx.x;
    const int s = (bid & 7) * (nwg >> 3) + (bid >> 3);
    const int bx = s & 7, by = s >> 3;  // GX = N/256 = 8

    const int KT = K >> 5;
    const int NT = K >> 6;  // K-tiles of 64
    const int pa = by * 2, pb = bx * 2;

    stage_tile256(A, B, sA[0], sB[0], pa, pb, KT, 0, w, l);
    __builtin_amdgcn_sched_barrier(0);
    stage_tile256(A, B, sA[1], sB[1], pa, pb, KT, 1, w, l);
    asm volatile("s_waitcnt vmcnt(8)" ::: "memory");
    __builtin_amdgcn_s_barrier();

    f32x4 acc[8][4] = {};

    for (int t = 0; t < NT; ++t) {
        const bf16_t* sa = sA[t & 1];
        const bf16_t* sb = sB[t & 1];
        bf16x8 bfr[4][2];
        bf16x8 af[2][2];

        // ---------------- phase 0: B full tile + A rows 0-1 ----------------
#pragma unroll
        for (int j = 0; j < 4; ++j)
#pragma unroll
            for (int k2 = 0; k2 < 2; ++k2)
                bfr[j][k2] = *(const bf16x8*)(
                    sb + ((((wn >> 1) * 2 + k2) * 8 + (wn & 1) * 4 + j) * 512) + l * 8);
#pragma unroll
        for (int ii = 0; ii < 2; ++ii)
#pragma unroll
            for (int k2 = 0; k2 < 2; ++k2)
                af[ii][k2] = *(const bf16x8*)(sa + (((wm * 2 + k2) * 8 + ii) * 512) + l * 8);
        __builtin_amdgcn_s_barrier();
        asm volatile("s_waitcnt lgkmcnt(0)" ::: "memory");
        __builtin_amdgcn_sched_barrier(0);
        __builtin_amdgcn_s_setprio(1);
#pragma unroll
        for (int ii = 0; ii < 2; ++ii)
#pragma unroll
            for (int j = 0; j < 4; ++j)
#pragma unroll
                for (int k2 = 0; k2 < 2; ++k2)
                    acc[ii][j] = __builtin_amdgcn_mfma_f32_16x16x32_bf16(
                        af[ii][k2], bfr[j][k2], acc[ii][j], 0, 0, 0);
        __builtin_amdgcn_s_setprio(0);
        __builtin_amdgcn_s_barrier();

        // ---------------- phases 1,2: A rows 2-3 / 4-5 ----------------
#pragma unroll
        for (int q = 1; q <= 2; ++q) {
#pragma unroll
            for (int ii = 0; ii < 2; ++ii)
#pragma unroll
                for (int k2 = 0; k2 < 2; ++k2)
                    af[ii][k2] = *(const bf16x8*)(
                        sa + (((wm * 2 + k2) * 8 + (q * 2 + ii)) * 512) + l * 8);
            __builtin_amdgcn_s_barrier();
            asm volatile("s_waitcnt lgkmcnt(0)" ::: "memory");
            __builtin_amdgcn_sched_barrier(0);
            __builtin_amdgcn_s_setprio(1);
#pragma unroll
            for (int ii = 0; ii < 2; ++ii)
#pragma unroll
                for (int j = 0; j < 4; ++j)
#pragma unroll
                    for (int k2 = 0; k2 < 2; ++k2)
                        acc[q * 2 + ii][j] = __builtin_amdgcn_mfma_f32_16x16x32_bf16(
                            af[ii][k2], bfr[j][k2], acc[q * 2 + ii][j], 0, 0, 0);
            __builtin_amdgcn_s_setprio(0);
            __builtin_amdgcn_s_barrier();
        }

        // ---------------- phase 3: A rows 6-7 + handoff + prefetch ----------------
#pragma unroll
        for (int ii = 0; ii < 2; ++ii)
#pragma unroll
            for (int k2 = 0; k2 < 2; ++k2)
                af[ii][k2] = *(const bf16x8*)(
                    sa + (((wm * 2 + k2) * 8 + (6 + ii)) * 512) + l * 8);
        asm volatile("s_waitcnt lgkmcnt(0)" ::: "memory");
        __builtin_amdgcn_s_barrier();
        if (t + 2 < NT)
            stage_tile256(A, B, sA[t & 1], sB[t & 1], pa, pb, KT, t + 2, w, l);
        __builtin_amdgcn_sched_barrier(0);
        __builtin_amdgcn_s_setprio(1);
#pragma unroll
        for (int ii = 0; ii < 2; ++ii)
#pragma unroll
            for (int j = 0; j < 4; ++j)
#pragma unroll
                for (int k2 = 0; k2 < 2; ++k2)
                    acc[6 + ii][j] = __builtin_amdgcn_mfma_f32_16x16x32_bf16(
                        af[ii][k2], bfr[j][k2], acc[6 + ii][j], 0, 0, 0);
        __builtin_amdgcn_s_setprio(0);
        if (t + 2 < NT)
            asm volatile("s_waitcnt vmcnt(8)" ::: "memory");
        else
            asm volatile("s_waitcnt vmcnt(0)" ::: "memory");
        __builtin_amdgcn_s_barrier();
    }

    // ---- epilogue ----
#pragma unroll
    for (int i = 0; i < 8; ++i) {
#pragma unroll
        for (int j = 0; j < 4; ++j) {
            const int col = bx * 256 + wn * 64 + j * 16 + lm;
            const float bv = bias[col];
#pragma unroll
            for (int r = 0; r < 4; ++r) {
                const int row = by * 256 + wm * 128 + i * 16 + quad * 4 + r;
                epi_store<MODE>(C, N, row, col, acc[i][j][r] + bv);
            }
        }
    }
}

// ---------------------------------------------------------------------------
// kv GEMM: 64x128 tile, BK=64, 4 waves (2x2: wave = 32 rows x 64 cols).
// ---------------------------------------------------------------------------
__global__ __launch_bounds__(256) void gemm_kv(const bf16_t* __restrict__ A,
                                               const bf16_t* __restrict__ B,
                                               const float* __restrict__ bias,
                                               bf16_t* __restrict__ C,
                                               int N, int K) {
    __shared__ __align__(16) bf16_t sA[4096];  // 8 chunks (64 rows x 64 k)
    __shared__ __align__(16) bf16_t sB[8192];  // 16 chunks

    const int tid = threadIdx.x;
    const int l = tid & 63, w = tid >> 6;
    const int lm = l & 15, quad = l >> 4;
    const int wm = w & 1, wn = w >> 1;
    const int KT = K >> 5;
    const int p = blockIdx.y >> 1, hh = blockIdx.y & 1;  // 64-row half of 128-panel
    const size_t aPan = (size_t)p * KT * 8 * 512;
    const size_t bBase = (size_t)blockIdx.x * KT * 8 * 512;

    f32x4 acc[2][4] = {};
    const int NIT = K >> 6;
    for (int kt = 0; kt < NIT; ++kt) {
        __syncthreads();
#pragma unroll
        for (int it = 0; it < 2; ++it) {
            const int lc = it * 4 + w;  // 0..7
            const int s = lc >> 2, cc = lc & 3;
            gld16(sA + lc * 512,
                  A + aPan + ((size_t)(kt * 2 + s) * 8 + hh * 4 + cc) * 512 + l * 8);
        }
#pragma unroll
        for (int it = 0; it < 4; ++it) {
            const int lc = it * 4 + w;  // 0..15
            gld16(sB + lc * 512, B + bBase + ((size_t)kt * 16 + lc) * 512 + l * 8);
        }
        __syncthreads();
#pragma unroll
        for (int s = 0; s < 2; ++s) {
            bf16x8 af[2], bfr[4];
#pragma unroll
            for (int i = 0; i < 2; ++i)
                af[i] = *(const bf16x8*)(sA + (s * 4 + wm * 2 + i) * 512 + l * 8);
#pragma unroll
            for (int j = 0; j < 4; ++j)
                bfr[j] = *(const bf16x8*)(sB + (s * 8 + wn * 4 + j) * 512 + l * 8);
#pragma unroll
            for (int i = 0; i < 2; ++i)
#pragma unroll
                for (int j = 0; j < 4; ++j)
                    acc[i][j] =
                        __builtin_amdgcn_mfma_f32_16x16x32_bf16(af[i], bfr[j], acc[i][j], 0, 0, 0);
        }
    }
#pragma unroll
    for (int i = 0; i < 2; ++i) {
#pragma unroll
        for (int j = 0; j < 4; ++j) {
            const int col = blockIdx.x * 128 + wn * 64 + j * 16 + lm;
            const float bv = bias[col];
#pragma unroll
            for (int r = 0; r < 4; ++r) {
                const int row = blockIdx.y * 64 + wm * 32 + i * 16 + quad * 4 + r;
                epi_store<2>(C, N, row, col, acc[i][j][r] + bv);
            }
        }
    }
}

// ---------------------------------------------------------------------------
// Fused attention, 64 q-rows per block.  R5: 64-key subgroups, double-
// buffered K/V staging with counted vmcnt; V prefetched under softmax;
// P double-buffered in sQP; setprio around MFMA clusters.
// LDS: 16 (sQP: Q then P-dbuf) + 32 (sKV dbuf) + 2 = 50KB.
// ---------------------------------------------------------------------------
__global__ __launch_bounds__(256, 2) void attn64(const bf16_t* __restrict__ qpk,
                                                 const bf16_t* __restrict__ kvpk,
                                                 bf16_t* __restrict__ o) {
    constexpr float SCALE = 0.08838834764831845f;  // 1/sqrt(128)
    __shared__ __align__(16) bf16_t sQP[8192];   // 16KB: Q (16 chunks) / P dbuf (2x8)
    __shared__ __align__(16) bf16_t sKV[16384];  // 32KB: 2 x 16-chunk buffers
    __shared__ float redM[4][64];
    __shared__ float redS[4][64];

    const int tid = threadIdx.x;
    const int l = tid & 63, w = tid >> 6;
    const int lm = l & 15, quad = l >> 4;
    const int b = blockIdx.z, h = blockIdx.y;
    const int p = blockIdx.x;  // 64-row q panel
    const int bh = b * 16 + h;
    const size_t qbase = ((size_t)bh * 64 + p) * 8192;
    const size_t kbase = (size_t)bh * 65536;
    const size_t vbase = 2097152 + (size_t)bh * 65536;

    // ---- prologue: stage Q [64 x 128] + K subgroup 0 ----
#pragma unroll
    for (int it = 0; it < 4; ++it) {
        const int c = it * 4 + w;
        gld16(sQP + c * 512, qpk + qbase + (size_t)c * 512 + l * 8);
    }
#pragma unroll
    for (int it = 0; it < 4; ++it) {
        const int c = it * 4 + w;
        gld16(sKV + c * 512, kvpk + kbase + (size_t)c * 512 + l * 8);
    }

    // ---- S = Q K^T over 8 key-subgroups of 64, double-buffered ----
    f32x4 sfr[8][4] = {};
#pragma unroll
    for (int sg = 0; sg < 8; ++sg) {
        if (sg < 7) {
            bf16_t* kn = sKV + (((sg + 1) & 1) << 13);
#pragma unroll
            for (int it = 0; it < 4; ++it) {
                const int c = it * 4 + w;
                gld16(kn + c * 512, kvpk + kbase + ((size_t)(sg + 1) * 16 + c) * 512 + l * 8);
            }
            asm volatile("s_waitcnt vmcnt(4)" ::: "memory");  // K[sg] (+Q at sg=0) landed
        } else {
            asm volatile("s_waitcnt vmcnt(0)" ::: "memory");
        }
        __builtin_amdgcn_s_barrier();  // publish K[sg]
        const bf16_t* kb = sKV + ((sg & 1) << 13);
        __builtin_amdgcn_s_setprio(1);
#pragma unroll
        for (int kc = 0; kc < 4; ++kc) {
            bf16x8 bb = *(const bf16x8*)(kb + (kc * 4 + w) * 512 + l * 8);
#pragma unroll
            for (int mt = 0; mt < 4; ++mt) {
                bf16x8 aa = *(const bf16x8*)(sQP + (kc * 4 + mt) * 512 + l * 8);
                sfr[sg][mt] =
                    __builtin_amdgcn_mfma_f32_16x16x32_bf16(aa, bb, sfr[sg][mt], 0, 0, 0);
            }
        }
        __builtin_amdgcn_s_setprio(0);
        asm volatile("s_waitcnt lgkmcnt(0)" ::: "memory");  // my reads of kb done
        __builtin_amdgcn_s_barrier();                        // all waves done reading kb
    }

    // ---- prefetch V subgroup 0 under the softmax ----
#pragma unroll
    for (int it = 0; it < 4; ++it) {
        const int c = it * 4 + w;
        gld16(sKV + c * 512, kvpk + vbase + (size_t)c * 512 + l * 8);
    }

    // ---- softmax (lgkm-only barriers: V0 stays in flight) ----
    float inv[4][4];
    {
        float mymax[4][4];
#pragma unroll
        for (int mt = 0; mt < 4; ++mt)
#pragma unroll
            for (int r = 0; r < 4; ++r) {
                float m = -3.0e38f;
#pragma unroll
                for (int t8 = 0; t8 < 8; ++t8) m = fmaxf(m, sfr[t8][mt][r]);
                m = fmaxf(m, __shfl_xor(m, 1));
                m = fmaxf(m, __shfl_xor(m, 2));
                m = fmaxf(m, __shfl_xor(m, 4));
                m = fmaxf(m, __shfl_xor(m, 8));
                mymax[mt][r] = m;
            }
        if (lm == 0) {
#pragma unroll
            for (int mt = 0; mt < 4; ++mt)
#pragma unroll
                for (int r = 0; r < 4; ++r)
                    redM[w][mt * 16 + quad * 4 + r] = mymax[mt][r];
        }
        asm volatile("s_waitcnt lgkmcnt(0)" ::: "memory");
        __builtin_amdgcn_s_barrier();
#pragma unroll
        for (int mt = 0; mt < 4; ++mt)
#pragma unroll
            for (int r = 0; r < 4; ++r) {
                const int row = mt * 16 + quad * 4 + r;
                const float M =
                    fmaxf(fmaxf(redM[0][row], redM[1][row]), fmaxf(redM[2][row], redM[3][row])) *
                    SCALE;
                float s = 0.f;
#pragma unroll
                for (int t8 = 0; t8 < 8; ++t8) {
                    const float pe = __expf(sfr[t8][mt][r] * SCALE - M);
                    sfr[t8][mt][r] = pe;
                    s += pe;
                }
                s += __shfl_xor(s, 1);
                s += __shfl_xor(s, 2);
                s += __shfl_xor(s, 4);
                s += __shfl_xor(s, 8);
                if (lm == 0) redS[w][row] = s;
            }
        asm volatile("s_waitcnt lgkmcnt(0)" ::: "memory");
        __builtin_amdgcn_s_barrier();
#pragma unroll
        for (int mt = 0; mt < 4; ++mt)
#pragma unroll
            for (int r = 0; r < 4; ++r) {
                const int row = mt * 16 + quad * 4 + r;
                inv[mt][r] = 1.f / (redS[0][row] + redS[1][row] + redS[2][row] + redS[3][row]);
            }
    }

    // ---- O = P V over 8 key-subgroups of 64, double-buffered ----
    // P chunk (within region (sg&1)*8): mt*2 + (key>>5); element
    // (quadp*16 + row16)*8 + jd with key = w*16 + lm, quadp = (w&1)*2+(lm>>3).
    const int kvh = w >> 1;
    const int quadp = (w & 1) * 2 + (lm >> 3);
    const int jd = lm & 7;
#define PWRITE(sg_) do {                                                          \
    const int r8_ = ((sg_) & 1) * 8;                                              \
    _Pragma("unroll") for (int mt = 0; mt < 4; ++mt)                              \
    _Pragma("unroll") for (int r = 0; r < 4; ++r)                                 \
        sQP[(r8_ + mt * 2 + kvh) * 512 + (quadp * 16 + quad * 4 + r) * 8 + jd] =  \
            (bf16_t)sfr[sg_][mt][r];                                              \
} while (0)

    f32x4 oc[4][2] = {};
    PWRITE(0);  // Q region dead (S-phase ended with lgkm0+barrier)
#pragma unroll
    for (int sg = 0; sg < 8; ++sg) {
        if (sg < 7) {
            bf16_t* vn = sKV + (((sg + 1) & 1) << 13);
#pragma unroll
            for (int it = 0; it < 4; ++it) {
                const int c = it * 4 + w;
                gld16(vn + c * 512, kvpk + vbase + ((size_t)(sg + 1) * 16 + c) * 512 + l * 8);
            }
            PWRITE(sg + 1);
            asm volatile("s_waitcnt vmcnt(4)" ::: "memory");  // V[sg] landed
        } else {
            asm volatile("s_waitcnt vmcnt(0)" ::: "memory");
        }
        asm volatile("s_waitcnt lgkmcnt(0)" ::: "memory");  // P writes drained
        __builtin_amdgcn_s_barrier();                        // publish V[sg], P[sg]
        const bf16_t* vb = sKV + ((sg & 1) << 13);
        const bf16_t* pb = sQP + ((sg & 1) << 12);
        __builtin_amdgcn_s_setprio(1);
#pragma unroll
        for (int kvf2 = 0; kvf2 < 2; ++kvf2) {
            bf16x8 aa[4];
#pragma unroll
            for (int mt = 0; mt < 4; ++mt)
                aa[mt] = *(const bf16x8*)(pb + (mt * 2 + kvf2) * 512 + l * 8);
#pragma unroll
            for (int ni = 0; ni < 2; ++ni) {
                bf16x8 bb = *(const bf16x8*)(vb + (kvf2 * 8 + w * 2 + ni) * 512 + l * 8);
#pragma unroll
                for (int mt = 0; mt < 4; ++mt)
                    oc[mt][ni] =
                        __builtin_amdgcn_mfma_f32_16x16x32_bf16(aa[mt], bb, oc[mt][ni], 0, 0, 0);
            }
        }
        __builtin_amdgcn_s_setprio(0);
        asm volatile("s_waitcnt lgkmcnt(0)" ::: "memory");  // my reads of vb/pb done
        __builtin_amdgcn_s_barrier();                        // all waves done reading
    }
#undef PWRITE

    // ---- epilogue: normalize, write natural-layout o ----
#pragma unroll
    for (int mt = 0; mt < 4; ++mt)
#pragma unroll
        for (int ni = 0; ni < 2; ++ni)
#pragma unroll
            for (int r = 0; r < 4; ++r) {
                const int row = mt * 16 + quad * 4 + r;
                const int d = w * 32 + ni * 16 + lm;
                o[((size_t)b * 4096 + p * 64 + row) * 2048 + h * 128 + d] =
                    (bf16_t)(oc[mt][ni][r] * inv[mt][r]);
            }
}

// ---------------------------------------------------------------------------
extern "C" void kernel_launch(void* const* d_in, const int* in_sizes, int n_in,
                              void* d_out, int out_size, void* d_ws, size_t ws_size,
                              hipStream_t stream) {
    (void)in_sizes; (void)n_in; (void)out_size; (void)ws_size;
    const float* x    = (const float*)d_in[0];
    const float* cond = (const float*)d_in[1];
    const float* wq   = (const float*)d_in[2];
    const float* bq   = (const float*)d_in[3];
    const float* wkv  = (const float*)d_in[4];
    const float* bkv  = (const float*)d_in[5];
    const float* wp   = (const float*)d_in[6];
    const float* bp   = (const float*)d_in[7];

    const size_t MB = 1ull << 20;
    uint8_t* ws = (uint8_t*)d_ws;
    bf16_t* qxpk   = (bf16_t*)(ws + 0);        // 32MB qdq(x) packed; reused as o natural
    bf16_t* qpk    = (bf16_t*)(ws + 32 * MB);  // 32MB q packed; reused as qdq(o) packed
    bf16_t* wqpk   = (bf16_t*)(ws + 64 * MB);  // 8MB
    bf16_t* wkvpk  = (bf16_t*)(ws + 72 * MB);  // 16MB
    bf16_t* wppk   = (bf16_t*)(ws + 88 * MB);  // 8MB
    bf16_t* condpk = (bf16_t*)(ws + 96 * MB);  // 4MB
    bf16_t* kvpk   = (bf16_t*)(ws + 100 * MB); // 8MB (K 4MB | V 4MB)
    bf16_t* o_nat  = qxpk;
    bf16_t* opk    = qpk;

    dim3 blk(256);
    rowpack<1, float><<<8192, blk, 0, stream>>>(x, qxpk, 2048);
    rowpack<1, float><<<2048, blk, 0, stream>>>(wq, wqpk, 2048);
    rowpack<1, float><<<2048, blk, 0, stream>>>(wp, wppk, 2048);
    rowpack<0, float><<<1024, blk, 0, stream>>>(cond, condpk, 2048);
    rowpack<0, float><<<4096, blk, 0, stream>>>(wkv, wkvpk, 2048);
    // q = qdq(x) qdq(wq)^T + bq  -> attention-packed (256^2 8-wave pipeline)
    gemm_pk8<0><<<dim3(256), dim3(512), 0, stream>>>(qxpk, wqpk, bq, qpk, 2048, 2048);
    // kv = cond wkv^T + bkv      -> packed K | packed V
    gemm_kv<<<dim3(32, 16), blk, 0, stream>>>(condpk, wkvpk, bkv, kvpk, 4096, 2048);
    // attention -> o natural (pipelined subgroup schedule)
    attn64<<<dim3(64, 16, 2), blk, 0, stream>>>(qpk, kvpk, o_nat);
    // qdq(o) packed
    rowpack<1, bf16_t><<<8192, blk, 0, stream>>>(o_nat, opk, 2048);
    // out = qdq(o) qdq(wp)^T + bp -> natural fp32 (256^2 8-wave pipeline)
    gemm_pk8<1><<<dim3(256), dim3(512), 0, stream>>>(opk, wppk, bp, (float*)d_out, 2048, 2048);
}

// Round 3
// 512.594 us; speedup vs baseline: 1.0007x; 1.0007x over previous
//
#include <hip/hip_runtime.h>
#include <cstdint>
#include <cstddef>

// ---------------------------------------------------------------------------
// MultiHeadCrossAttention W8A8 fake-quant, MI355X (gfx950)
// B=2, N=4096, M=512, C=2048, H=16, Dh=128
//
// R6: attn64 with Q-in-registers + distance-2 prefetch:
//   - Q fragments hoisted to 64 VGPRs once (S-phase LDS reads 20 -> 4/phase)
//   - uniform 16-phase pipeline (8 K + 8 V subgroups of 64 keys), THREE
//     16KB sKV buffers: slot n's 4 gld16 issued at phase n-2 -> ~2 phases
//     of flight (>= L2 latency).  Steady-state wait vmcnt(8); never a cold
//     drain until the last two phases.
//   - V0/V1 issued during K-phases 6/7, flying under the whole softmax.
//   - P double-buffered in sQP (Q region dead after the reg hoist).
//   - setprio(1/0) around each 16-MFMA cluster.
//   LDS: 16 (sQP) + 48 (sKV x3) + 2 = 66KB -> 2 blocks/CU.
// gemm_pk8 (R4 deep pipeline) unchanged.
//
// GEMM-operand pack (M x K, 128-row panels, 32-col chunk groups):
//   idx(row,col) = ((p*KT + kt)*8 + c)*512 + (quad*16 + lm)*8 + j
//   p=row>>7, c=(row>>4)&7, lm=row&15, kt=col>>5, quad=(col>>3)&3, j=col&7
// ---------------------------------------------------------------------------

typedef __bf16 bf16_t;
typedef __bf16 bf16x8 __attribute__((ext_vector_type(8)));
typedef float f32x4 __attribute__((ext_vector_type(4)));

__device__ __forceinline__ void gld16(void* lds, const void* g) {
    __builtin_amdgcn_global_load_lds(
        (__attribute__((address_space(1))) uint32_t*)(uintptr_t)g,
        (__attribute__((address_space(3))) uint32_t*)(uint32_t)(uintptr_t)lds,
        16, 0, 0);
}

__device__ __forceinline__ void load8(const float* p, int i, float* v) {
    const float4* p4 = (const float4*)p;
    float4 a = p4[2 * i], b = p4[2 * i + 1];
    v[0] = a.x; v[1] = a.y; v[2] = a.z; v[3] = a.w;
    v[4] = b.x; v[5] = b.y; v[6] = b.z; v[7] = b.w;
}
__device__ __forceinline__ void load8(const bf16_t* p, int i, float* v) {
    bf16x8 t = ((const bf16x8*)p)[i];
#pragma unroll
    for (int j = 0; j < 8; ++j) v[j] = (float)t[j];
}

// ---------------------------------------------------------------------------
// Per-row fake-quant (QUANT=1) or plain convert (QUANT=0), output packed.
// ---------------------------------------------------------------------------
template <int QUANT, typename T>
__global__ __launch_bounds__(256) void rowpack(const T* __restrict__ in,
                                               bf16_t* __restrict__ out, int K) {
    const int tid = threadIdx.x;
    const size_t row = blockIdx.x;
    const T* rp = in + row * (size_t)K;
    const int n8 = K >> 3;
    float scale = 1.0f;
    if (QUANT) {
        float m = 0.f;
        for (int i = tid; i < n8; i += 256) {
            float v[8];
            load8(rp, i, v);
#pragma unroll
            for (int j = 0; j < 8; ++j) m = fmaxf(m, fabsf(v[j]));
        }
        __shared__ float red[256];
        red[tid] = m;
        __syncthreads();
        for (int s = 128; s > 0; s >>= 1) {
            if (tid < s) red[tid] = fmaxf(red[tid], red[tid + s]);
            __syncthreads();
        }
        scale = fmaxf(red[0] * (1.0f / 127.0f), 1e-8f);
    }
    const int KT = K >> 5;
    const int p = (int)(row >> 7), c = ((int)row >> 4) & 7, lm = (int)row & 15;
    for (int i = tid; i < n8; i += 256) {
        const int col = i << 3;
        const int kt = col >> 5, quad = (col >> 3) & 3;
        float v[8];
        load8(rp, i, v);
        bf16x8 o8;
#pragma unroll
        for (int j = 0; j < 8; ++j) {
            float q = v[j];
            if (QUANT) {
                q = rintf(q / scale);  // RNE, matches jnp.round
                q = fminf(127.f, fmaxf(-127.f, q)) * scale;
            }
            o8[j] = (bf16_t)q;
        }
        const size_t dst = ((size_t)(p * KT + kt) * 8 + c) * 512 + (quad * 16 + lm) * 8;
        *(bf16x8*)(out + dst) = o8;
    }
}

// ---------------------------------------------------------------------------
// Epilogue stores (shared by the GEMM kernels).
// MODE 0: attention-packed q.  MODE 1: natural fp32.  MODE 2: kv split pack.
// ---------------------------------------------------------------------------
template <int MODE>
__device__ __forceinline__ void epi_store(void* C, int N, int row, int col, float v) {
    if (MODE == 1) {
        ((float*)C)[(size_t)row * N + col] = v;
    } else if (MODE == 0) {
        const int b = row >> 12, n = row & 4095;
        const int h = col >> 7, d = col & 127;
        const int p = n >> 6, mt = (n >> 4) & 3, lmq = n & 15;
        const int kq = d >> 5, qq = (d >> 3) & 3, jq = d & 7;
        const size_t idx = (((size_t)(b * 16 + h) * 64 + p) * 16 + kq * 4 + mt) * 512 +
                           (qq * 16 + lmq) * 8 + jq;
        ((bf16_t*)C)[idx] = (bf16_t)v;
    } else {
        const int b = row >> 9, m = row & 511;
        const int half = col >> 11, h = (col >> 7) & 15, d = col & 127;
        const int t8 = m >> 6;
        bf16_t* out = (bf16_t*)C;
        if (half == 0) {
            const int nt = (m >> 4) & 3, lmk = m & 15;
            const int kc = d >> 5, qk = (d >> 3) & 3, jk = d & 7;
            const size_t idx = (((size_t)(b * 16 + h) * 8 + t8) * 16 + kc * 4 + nt) * 512 +
                               (qk * 16 + lmk) * 8 + jk;
            out[idx] = (bf16_t)v;
        } else {
            const int kv2 = (m >> 5) & 1, qv = (m >> 3) & 3, jv = m & 7;
            const int ntv = d >> 4, lmv = d & 15;
            const size_t idx = 2097152 +
                (((size_t)(b * 16 + h) * 8 + t8) * 16 + kv2 * 8 + ntv) * 512 +
                (qv * 16 + lmv) * 8 + jv;
            out[idx] = (bf16_t)v;
        }
    }
}

// ---------------------------------------------------------------------------
// Stage one 256x64 K-tile pair (A and B) into LDS: 32 chunks each, 8 waves
// x 4 chunks, 8 gld16/thread.
// ---------------------------------------------------------------------------
__device__ __forceinline__ void stage_tile256(const bf16_t* __restrict__ A,
                                              const bf16_t* __restrict__ B,
                                              bf16_t* sa, bf16_t* sb,
                                              int pa, int pb, int KT, int t,
                                              int w, int l) {
#pragma unroll
    for (int it = 0; it < 4; ++it) {
        const int ci = w * 4 + it;                      // 0..31, wave-uniform
        const int h = ci >> 4, kt2 = (ci >> 3) & 1, c = ci & 7;
        const size_t ga = (((size_t)(pa + h) * KT + (2 * t + kt2)) * 8 + c) * 512 + l * 8;
        const size_t gb = (((size_t)(pb + h) * KT + (2 * t + kt2)) * 8 + c) * 512 + l * 8;
        gld16(sa + ci * 512, A + ga);
        gld16(sb + ci * 512, B + gb);
    }
}

// ---------------------------------------------------------------------------
// 256x256 deep-pipelined GEMM on packed operands: C = A B^T + bias.
// (unchanged from R4 — see header comment)
// ---------------------------------------------------------------------------
template <int MODE>
__global__ __launch_bounds__(512, 1) void gemm_pk8(const bf16_t* __restrict__ A,
                                                   const bf16_t* __restrict__ B,
                                                   const float* __restrict__ bias,
                                                   void* __restrict__ C,
                                                   int N, int K) {
    __shared__ __align__(16) bf16_t sA[2][16384];  // 2 x 32KB
    __shared__ __align__(16) bf16_t sB[2][16384];  // total 128KB -> 1 block/CU

    const int tid = threadIdx.x;
    const int l = tid & 63, w = tid >> 6;
    const int lm = l & 15, quad = l >> 4;
    const int wm = w & 1, wn = w >> 1;  // 2 x 4 wave grid

    const int nwg = gridDim.x;
    const int bid = blockIdx.x;
    const int s = (bid & 7) * (nwg >> 3) + (bid >> 3);
    const int bx = s & 7, by = s >> 3;  // GX = N/256 = 8

    const int KT = K >> 5;
    const int NT = K >> 6;  // K-tiles of 64
    const int pa = by * 2, pb = bx * 2;

    stage_tile256(A, B, sA[0], sB[0], pa, pb, KT, 0, w, l);
    __builtin_amdgcn_sched_barrier(0);
    stage_tile256(A, B, sA[1], sB[1], pa, pb, KT, 1, w, l);
    asm volatile("s_waitcnt vmcnt(8)" ::: "memory");
    __builtin_amdgcn_s_barrier();

    f32x4 acc[8][4] = {};

    for (int t = 0; t < NT; ++t) {
        const bf16_t* sa = sA[t & 1];
        const bf16_t* sb = sB[t & 1];
        bf16x8 bfr[4][2];
        bf16x8 af[2][2];

        // ---------------- phase 0: B full tile + A rows 0-1 ----------------
#pragma unroll
        for (int j = 0; j < 4; ++j)
#pragma unroll
            for (int k2 = 0; k2 < 2; ++k2)
                bfr[j][k2] = *(const bf16x8*)(
                    sb + ((((wn >> 1) * 2 + k2) * 8 + (wn & 1) * 4 + j) * 512) + l * 8);
#pragma unroll
        for (int ii = 0; ii < 2; ++ii)
#pragma unroll
            for (int k2 = 0; k2 < 2; ++k2)
                af[ii][k2] = *(const bf16x8*)(sa + (((wm * 2 + k2) * 8 + ii) * 512) + l * 8);
        __builtin_amdgcn_s_barrier();
        asm volatile("s_waitcnt lgkmcnt(0)" ::: "memory");
        __builtin_amdgcn_sched_barrier(0);
        __builtin_amdgcn_s_setprio(1);
#pragma unroll
        for (int ii = 0; ii < 2; ++ii)
#pragma unroll
            for (int j = 0; j < 4; ++j)
#pragma unroll
                for (int k2 = 0; k2 < 2; ++k2)
                    acc[ii][j] = __builtin_amdgcn_mfma_f32_16x16x32_bf16(
                        af[ii][k2], bfr[j][k2], acc[ii][j], 0, 0, 0);
        __builtin_amdgcn_s_setprio(0);
        __builtin_amdgcn_s_barrier();

        // ---------------- phases 1,2: A rows 2-3 / 4-5 ----------------
#pragma unroll
        for (int q = 1; q <= 2; ++q) {
#pragma unroll
            for (int ii = 0; ii < 2; ++ii)
#pragma unroll
                for (int k2 = 0; k2 < 2; ++k2)
                    af[ii][k2] = *(const bf16x8*)(
                        sa + (((wm * 2 + k2) * 8 + (q * 2 + ii)) * 512) + l * 8);
            __builtin_amdgcn_s_barrier();
            asm volatile("s_waitcnt lgkmcnt(0)" ::: "memory");
            __builtin_amdgcn_sched_barrier(0);
            __builtin_amdgcn_s_setprio(1);
#pragma unroll
            for (int ii = 0; ii < 2; ++ii)
#pragma unroll
                for (int j = 0; j < 4; ++j)
#pragma unroll
                    for (int k2 = 0; k2 < 2; ++k2)
                        acc[q * 2 + ii][j] = __builtin_amdgcn_mfma_f32_16x16x32_bf16(
                            af[ii][k2], bfr[j][k2], acc[q * 2 + ii][j], 0, 0, 0);
            __builtin_amdgcn_s_setprio(0);
            __builtin_amdgcn_s_barrier();
        }

        // ---------------- phase 3: A rows 6-7 + handoff + prefetch ----------------
#pragma unroll
        for (int ii = 0; ii < 2; ++ii)
#pragma unroll
            for (int k2 = 0; k2 < 2; ++k2)
                af[ii][k2] = *(const bf16x8*)(
                    sa + (((wm * 2 + k2) * 8 + (6 + ii)) * 512) + l * 8);
        asm volatile("s_waitcnt lgkmcnt(0)" ::: "memory");
        __builtin_amdgcn_s_barrier();
        if (t + 2 < NT)
            stage_tile256(A, B, sA[t & 1], sB[t & 1], pa, pb, KT, t + 2, w, l);
        __builtin_amdgcn_sched_barrier(0);
        __builtin_amdgcn_s_setprio(1);
#pragma unroll
        for (int ii = 0; ii < 2; ++ii)
#pragma unroll
            for (int j = 0; j < 4; ++j)
#pragma unroll
                for (int k2 = 0; k2 < 2; ++k2)
                    acc[6 + ii][j] = __builtin_amdgcn_mfma_f32_16x16x32_bf16(
                        af[ii][k2], bfr[j][k2], acc[6 + ii][j], 0, 0, 0);
        __builtin_amdgcn_s_setprio(0);
        if (t + 2 < NT)
            asm volatile("s_waitcnt vmcnt(8)" ::: "memory");
        else
            asm volatile("s_waitcnt vmcnt(0)" ::: "memory");
        __builtin_amdgcn_s_barrier();
    }

    // ---- epilogue ----
#pragma unroll
    for (int i = 0; i < 8; ++i) {
#pragma unroll
        for (int j = 0; j < 4; ++j) {
            const int col = bx * 256 + wn * 64 + j * 16 + lm;
            const float bv = bias[col];
#pragma unroll
            for (int r = 0; r < 4; ++r) {
                const int row = by * 256 + wm * 128 + i * 16 + quad * 4 + r;
                epi_store<MODE>(C, N, row, col, acc[i][j][r] + bv);
            }
        }
    }
}

// ---------------------------------------------------------------------------
// kv GEMM: 64x128 tile, BK=64, 4 waves (2x2: wave = 32 rows x 64 cols).
// ---------------------------------------------------------------------------
__global__ __launch_bounds__(256) void gemm_kv(const bf16_t* __restrict__ A,
                                               const bf16_t* __restrict__ B,
                                               const float* __restrict__ bias,
                                               bf16_t* __restrict__ C,
                                               int N, int K) {
    __shared__ __align__(16) bf16_t sA[4096];  // 8 chunks (64 rows x 64 k)
    __shared__ __align__(16) bf16_t sB[8192];  // 16 chunks

    const int tid = threadIdx.x;
    const int l = tid & 63, w = tid >> 6;
    const int lm = l & 15, quad = l >> 4;
    const int wm = w & 1, wn = w >> 1;
    const int KT = K >> 5;
    const int p = blockIdx.y >> 1, hh = blockIdx.y & 1;  // 64-row half of 128-panel
    const size_t aPan = (size_t)p * KT * 8 * 512;
    const size_t bBase = (size_t)blockIdx.x * KT * 8 * 512;

    f32x4 acc[2][4] = {};
    const int NIT = K >> 6;
    for (int kt = 0; kt < NIT; ++kt) {
        __syncthreads();
#pragma unroll
        for (int it = 0; it < 2; ++it) {
            const int lc = it * 4 + w;  // 0..7
            const int s = lc >> 2, cc = lc & 3;
            gld16(sA + lc * 512,
                  A + aPan + ((size_t)(kt * 2 + s) * 8 + hh * 4 + cc) * 512 + l * 8);
        }
#pragma unroll
        for (int it = 0; it < 4; ++it) {
            const int lc = it * 4 + w;  // 0..15
            gld16(sB + lc * 512, B + bBase + ((size_t)kt * 16 + lc) * 512 + l * 8);
        }
        __syncthreads();
#pragma unroll
        for (int s = 0; s < 2; ++s) {
            bf16x8 af[2], bfr[4];
#pragma unroll
            for (int i = 0; i < 2; ++i)
                af[i] = *(const bf16x8*)(sA + (s * 4 + wm * 2 + i) * 512 + l * 8);
#pragma unroll
            for (int j = 0; j < 4; ++j)
                bfr[j] = *(const bf16x8*)(sB + (s * 8 + wn * 4 + j) * 512 + l * 8);
#pragma unroll
            for (int i = 0; i < 2; ++i)
#pragma unroll
                for (int j = 0; j < 4; ++j)
                    acc[i][j] =
                        __builtin_amdgcn_mfma_f32_16x16x32_bf16(af[i], bfr[j], acc[i][j], 0, 0, 0);
        }
    }
#pragma unroll
    for (int i = 0; i < 2; ++i) {
#pragma unroll
        for (int j = 0; j < 4; ++j) {
            const int col = blockIdx.x * 128 + wn * 64 + j * 16 + lm;
            const float bv = bias[col];
#pragma unroll
            for (int r = 0; r < 4; ++r) {
                const int row = blockIdx.y * 64 + wm * 32 + i * 16 + quad * 4 + r;
                epi_store<2>(C, N, row, col, acc[i][j][r] + bv);
            }
        }
    }
}

// ---------------------------------------------------------------------------
// Fused attention, 64 q-rows per block.  R6: Q in registers, 16-phase
// uniform pipeline with 3-buffer distance-2 K/V prefetch, counted vmcnt.
// LDS: 16 (sQP: Q then P-dbuf) + 48 (sKV x3) + 2 = 66KB -> 2 blocks/CU.
// ---------------------------------------------------------------------------
__global__ __launch_bounds__(256, 2) void attn64(const bf16_t* __restrict__ qpk,
                                                 const bf16_t* __restrict__ kvpk,
                                                 bf16_t* __restrict__ o) {
    constexpr float SCALE = 0.08838834764831845f;  // 1/sqrt(128)
    __shared__ __align__(16) bf16_t sQP[8192];   // 16KB: Q (16 chunks) / P dbuf (2x8)
    __shared__ __align__(16) bf16_t sKV[24576];  // 48KB: 3 x 16-chunk buffers
    __shared__ float redM[4][64];
    __shared__ float redS[4][64];

    const int tid = threadIdx.x;
    const int l = tid & 63, w = tid >> 6;
    const int lm = l & 15, quad = l >> 4;
    const int b = blockIdx.z, h = blockIdx.y;
    const int p = blockIdx.x;  // 64-row q panel
    const int bh = b * 16 + h;
    const size_t qbase = ((size_t)bh * 64 + p) * 8192;
    const size_t kbase = (size_t)bh * 65536;
    const size_t vbase = 2097152 + (size_t)bh * 65536;

    // pipeline slot n: n<8 -> K subgroup n; n>=8 -> V subgroup n-8.
    // buffer = n%3.  Wave w issues chunks {w, 4+w, 8+w, 12+w}.
    auto issue = [&](int n) {
        bf16_t* dst = sKV + (n % 3) * 8192;
        const size_t src = (n < 8) ? kbase + (size_t)n * 8192
                                   : vbase + (size_t)(n - 8) * 8192;
#pragma unroll
        for (int it = 0; it < 4; ++it) {
            const int c = it * 4 + w;
            gld16(dst + c * 512, kvpk + src + (size_t)c * 512 + l * 8);
        }
    };

    // ---- prologue: L0 = Q(4) + K0(4) [8 vm instr], then L1 = K1(4) ----
#pragma unroll
    for (int it = 0; it < 4; ++it) {
        const int c = it * 4 + w;
        gld16(sQP + c * 512, qpk + qbase + (size_t)c * 512 + l * 8);
    }
    issue(0);
    __builtin_amdgcn_sched_barrier(0);  // keep Q+K0 oldest in the vm queue
    issue(1);

    bf16x8 qf[4][4];       // Q fragments, 64 VGPR, loaded once in phase 0
    f32x4 sfr[8][4] = {};  // S accumulators

    // ---- S = Q K^T: phases 0..7 ----
#pragma unroll
    for (int sg = 0; sg < 8; ++sg) {
        issue(sg + 2);  // K2..K7, then V0 (sg=6), V1 (sg=7)
        asm volatile("s_waitcnt vmcnt(8)" ::: "memory");  // slot sg landed
        __builtin_amdgcn_s_barrier();                      // publish slot sg
        __builtin_amdgcn_sched_barrier(0);
        const bf16_t* kb = sKV + (sg % 3) * 8192;
        if (sg == 0) {
#pragma unroll
            for (int kc = 0; kc < 4; ++kc)
#pragma unroll
                for (int mt = 0; mt < 4; ++mt)
                    qf[kc][mt] = *(const bf16x8*)(sQP + (kc * 4 + mt) * 512 + l * 8);
        }
        __builtin_amdgcn_s_setprio(1);
#pragma unroll
        for (int kc = 0; kc < 4; ++kc) {
            bf16x8 bb = *(const bf16x8*)(kb + (kc * 4 + w) * 512 + l * 8);
#pragma unroll
            for (int mt = 0; mt < 4; ++mt)
                sfr[sg][mt] =
                    __builtin_amdgcn_mfma_f32_16x16x32_bf16(qf[kc][mt], bb, sfr[sg][mt], 0, 0, 0);
        }
        __builtin_amdgcn_s_setprio(0);
        asm volatile("s_waitcnt lgkmcnt(0)" ::: "memory");  // my reads of kb done
        __builtin_amdgcn_s_barrier();                        // all waves done reading kb
    }

    // ---- softmax (V0,V1 in flight; barriers are lgkm-only) ----
    float inv[4][4];
    {
        float mymax[4][4];
#pragma unroll
        for (int mt = 0; mt < 4; ++mt)
#pragma unroll
            for (int r = 0; r < 4; ++r) {
                float m = -3.0e38f;
#pragma unroll
                for (int t8 = 0; t8 < 8; ++t8) m = fmaxf(m, sfr[t8][mt][r]);
                m = fmaxf(m, __shfl_xor(m, 1));
                m = fmaxf(m, __shfl_xor(m, 2));
                m = fmaxf(m, __shfl_xor(m, 4));
                m = fmaxf(m, __shfl_xor(m, 8));
                mymax[mt][r] = m;
            }
        if (lm == 0) {
#pragma unroll
            for (int mt = 0; mt < 4; ++mt)
#pragma unroll
                for (int r = 0; r < 4; ++r)
                    redM[w][mt * 16 + quad * 4 + r] = mymax[mt][r];
        }
        asm volatile("s_waitcnt lgkmcnt(0)" ::: "memory");
        __builtin_amdgcn_s_barrier();
#pragma unroll
        for (int mt = 0; mt < 4; ++mt)
#pragma unroll
            for (int r = 0; r < 4; ++r) {
                const int row = mt * 16 + quad * 4 + r;
                const float M =
                    fmaxf(fmaxf(redM[0][row], redM[1][row]), fmaxf(redM[2][row], redM[3][row])) *
                    SCALE;
                float s = 0.f;
#pragma unroll
                for (int t8 = 0; t8 < 8; ++t8) {
                    const float pe = __expf(sfr[t8][mt][r] * SCALE - M);
                    sfr[t8][mt][r] = pe;
                    s += pe;
                }
                s += __shfl_xor(s, 1);
                s += __shfl_xor(s, 2);
                s += __shfl_xor(s, 4);
                s += __shfl_xor(s, 8);
                if (lm == 0) redS[w][row] = s;
            }
        asm volatile("s_waitcnt lgkmcnt(0)" ::: "memory");
        __builtin_amdgcn_s_barrier();
#pragma unroll
        for (int mt = 0; mt < 4; ++mt)
#pragma unroll
            for (int r = 0; r < 4; ++r) {
                const int row = mt * 16 + quad * 4 + r;
                inv[mt][r] = 1.f / (redS[0][row] + redS[1][row] + redS[2][row] + redS[3][row]);
            }
    }

    // ---- O = P V: phases 8..15 ----
    const int kvh = w >> 1;
    const int quadp = (w & 1) * 2 + (lm >> 3);
    const int jd = lm & 7;
#define PWRITE(sg_) do {                                                          \
    const int r8_ = ((sg_) & 1) * 8;                                              \
    _Pragma("unroll") for (int mt = 0; mt < 4; ++mt)                              \
    _Pragma("unroll") for (int r = 0; r < 4; ++r)                                 \
        sQP[(r8_ + mt * 2 + kvh) * 512 + (quadp * 16 + quad * 4 + r) * 8 + jd] =  \
            (bf16_t)sfr[sg_][mt][r];                                              \
} while (0)

    f32x4 oc[4][2] = {};
    PWRITE(0);  // Q region dead (reg-hoisted; all reads drained at phase-0 end)
#pragma unroll
    for (int sg = 0; sg < 8; ++sg) {
        if (sg < 6) issue(sg + 10);   // V2..V7
        if (sg < 7) PWRITE(sg + 1);
        if (sg < 6)
            asm volatile("s_waitcnt vmcnt(8)" ::: "memory");  // V[sg] landed
        else if (sg == 6)
            asm volatile("s_waitcnt vmcnt(4)" ::: "memory");
        else
            asm volatile("s_waitcnt vmcnt(0)" ::: "memory");
        asm volatile("s_waitcnt lgkmcnt(0)" ::: "memory");  // P writes drained
        __builtin_amdgcn_s_barrier();                        // publish V[sg], P[sg]
        __builtin_amdgcn_sched_barrier(0);
        const bf16_t* vb = sKV + ((sg + 8) % 3) * 8192;
        const bf16_t* pb = sQP + ((sg & 1) << 12);
        __builtin_amdgcn_s_setprio(1);
#pragma unroll
        for (int kvf2 = 0; kvf2 < 2; ++kvf2) {
            bf16x8 aa[4];
#pragma unroll
            for (int mt = 0; mt < 4; ++mt)
                aa[mt] = *(const bf16x8*)(pb + (mt * 2 + kvf2) * 512 + l * 8);
#pragma unroll
            for (int ni = 0; ni < 2; ++ni) {
                bf16x8 bb = *(const bf16x8*)(vb + (kvf2 * 8 + w * 2 + ni) * 512 + l * 8);
#pragma unroll
                for (int mt = 0; mt < 4; ++mt)
                    oc[mt][ni] =
                        __builtin_amdgcn_mfma_f32_16x16x32_bf16(aa[mt], bb, oc[mt][ni], 0, 0, 0);
            }
        }
        __builtin_amdgcn_s_setprio(0);
        asm volatile("s_waitcnt lgkmcnt(0)" ::: "memory");  // my reads of vb/pb done
        __builtin_amdgcn_s_barrier();                        // all waves done reading
    }
#undef PWRITE

    // ---- epilogue: normalize, write natural-layout o ----
#pragma unroll
    for (int mt = 0; mt < 4; ++mt)
#pragma unroll
        for (int ni = 0; ni < 2; ++ni)
#pragma unroll
            for (int r = 0; r < 4; ++r) {
                const int row = mt * 16 + quad * 4 + r;
                const int d = w * 32 + ni * 16 + lm;
                o[((size_t)b * 4096 + p * 64 + row) * 2048 + h * 128 + d] =
                    (bf16_t)(oc[mt][ni][r] * inv[mt][r]);
            }
}

// ---------------------------------------------------------------------------
extern "C" void kernel_launch(void* const* d_in, const int* in_sizes, int n_in,
                              void* d_out, int out_size, void* d_ws, size_t ws_size,
                              hipStream_t stream) {
    (void)in_sizes; (void)n_in; (void)out_size; (void)ws_size;
    const float* x    = (const float*)d_in[0];
    const float* cond = (const float*)d_in[1];
    const float* wq   = (const float*)d_in[2];
    const float* bq   = (const float*)d_in[3];
    const float* wkv  = (const float*)d_in[4];
    const float* bkv  = (const float*)d_in[5];
    const float* wp   = (const float*)d_in[6];
    const float* bp   = (const float*)d_in[7];

    const size_t MB = 1ull << 20;
    uint8_t* ws = (uint8_t*)d_ws;
    bf16_t* qxpk   = (bf16_t*)(ws + 0);        // 32MB qdq(x) packed; reused as o natural
    bf16_t* qpk    = (bf16_t*)(ws + 32 * MB);  // 32MB q packed; reused as qdq(o) packed
    bf16_t* wqpk   = (bf16_t*)(ws + 64 * MB);  // 8MB
    bf16_t* wkvpk  = (bf16_t*)(ws + 72 * MB);  // 16MB
    bf16_t* wppk   = (bf16_t*)(ws + 88 * MB);  // 8MB
    bf16_t* condpk = (bf16_t*)(ws + 96 * MB);  // 4MB
    bf16_t* kvpk   = (bf16_t*)(ws + 100 * MB); // 8MB (K 4MB | V 4MB)
    bf16_t* o_nat  = qxpk;
    bf16_t* opk    = qpk;

    dim3 blk(256);
    rowpack<1, float><<<8192, blk, 0, stream>>>(x, qxpk, 2048);
    rowpack<1, float><<<2048, blk, 0, stream>>>(wq, wqpk, 2048);
    rowpack<1, float><<<2048, blk, 0, stream>>>(wp, wppk, 2048);
    rowpack<0, float><<<1024, blk, 0, stream>>>(cond, condpk, 2048);
    rowpack<0, float><<<4096, blk, 0, stream>>>(wkv, wkvpk, 2048);
    // q = qdq(x) qdq(wq)^T + bq  -> attention-packed (256^2 8-wave pipeline)
    gemm_pk8<0><<<dim3(256), dim3(512), 0, stream>>>(qxpk, wqpk, bq, qpk, 2048, 2048);
    // kv = cond wkv^T + bkv      -> packed K | packed V
    gemm_kv<<<dim3(32, 16), blk, 0, stream>>>(condpk, wkvpk, bkv, kvpk, 4096, 2048);
    // attention -> o natural (Q-in-reg, distance-2 prefetch pipeline)
    attn64<<<dim3(64, 16, 2), blk, 0, stream>>>(qpk, kvpk, o_nat);
    // qdq(o) packed
    rowpack<1, bf16_t><<<8192, blk, 0, stream>>>(o_nat, opk, 2048);
    // out = qdq(o) qdq(wp)^T + bp -> natural fp32 (256^2 8-wave pipeline)
    gemm_pk8<1><<<dim3(256), dim3(512), 0, stream>>>(opk, wppk, bp, (float*)d_out, 2048, 2048);
}